// Round 9
// baseline (49.776 us; speedup 1.0000x reference)
//
#include <hip/hip_runtime.h>
#include <math.h>

// B=16, T=64, R=256, C=16, D=16, O(=in_dim)=16, NUM_ITERATIONS=3
//
// Factorization: u_hat[b,t,r,c,o] = Wsum[r,c,o]*usum[b,t]
//   Wsum[r,c,o] = sum_d W[r,c,d,o], usum[b,t] = sum_i ui[b,t,i]
// Per iter: cij = softmax_c(bij); S[c,o] = sum_r cij[r,c]*Wsum[r,c,o]
//   NS[c] = sum_o S^2; Ts[c] = sum_t us^2*squash_scale(us^2*NS[c])
//   bij[r,c] += (sum_o Wsum[r,c,o]*S[c,o]) * Ts[c]
// Output: v[b,t,c,o] = squash_scale(us^2*NS[c])*us*S[c,o]
//
// R8 lesson: pass-count over Wsum is k2's cost (256KB per pass, per-CU pipe).
// R7 = 5 passes (3B+2E). Here: S0 via k1 atomicAdd (0 passes in k2),
// E0/E1 + softmax fully register-resident (w[4][16] VGPRs, 1 load pass),
// B1/B2 stream WT with in-stream accumulate. k2 = 3 passes total.

#define OFF_WS 0       // Wsum  [r][co]  256x256
#define OFF_WT 65536   // WsumT [co][r]  256x256
#define OFF_S0 131072  // sum_r Wsum [co] (atomicAdd; memset to 0 per call)

__device__ __forceinline__ float squash_scale(float n2) {
    return n2 / (1.0f + n2) * rsqrtf(n2 + 1e-9f);
}

// K1: both Wsum layouts + column-sum for S0. grid 256x256.
__global__ void k1_prep(const float* __restrict__ W, float* __restrict__ ws) {
    const int r = blockIdx.x, tid = threadIdx.x;   // tid = c*16+o
    const int c = tid >> 4, o = tid & 15;
    const float* base = W + r * 4096 + c * 256 + o;
    float s = 0.f;
#pragma unroll
    for (int d = 0; d < 16; ++d) s += base[d * 16];
    ws[OFF_WS + r * 256 + tid] = s;
    ws[OFF_WT + tid * 256 + r] = s;
    atomicAdd(ws + OFF_S0 + tid, s);
}

// K2: full routing, one block per b. grid 16 x 1024.
__global__ void __launch_bounds__(1024, 1) k2_route(
    const float* __restrict__ ui, const float* __restrict__ ws,
    float* __restrict__ out)
{
    __shared__ __align__(16) float cijT[16][260];    // [c][r]
    __shared__ __align__(16) float S_sh[256];        // [c*16+o]
    __shared__ float Ts_sh[16];
    __shared__ float usum_sh[64];

    const int b = blockIdx.x, tid = threadIdx.x;
    const int r = tid >> 2, cg = tid & 3;            // E/load map: 4 c's per thread
    const int wv = tid >> 6, ln = tid & 63;          // B/Ts map: wave = c

    // ---- load: w[j][o4] = Wsum[r][cg*4+j][o4*4..+3] into 16 float4 regs ----
    float4 wreg[16];
    {
        const float* wbase = ws + OFF_WS + r * 256 + cg * 64;
#pragma unroll
        for (int j = 0; j < 4; ++j)
#pragma unroll
            for (int o4 = 0; o4 < 4; ++o4)
                wreg[j * 4 + o4] = *(const float4*)(wbase + j * 16 + o4 * 4);
    }
    if (tid < 64) {
        const float4* u4 = (const float4*)(ui + b * 1024 + tid * 16);
        float4 a = u4[0], e = u4[1], f = u4[2], g = u4[3];
        usum_sh[tid] = ((a.x + a.y) + (a.z + a.w)) + ((e.x + e.y) + (e.z + e.w))
                     + ((f.x + f.y) + (f.z + f.w)) + ((g.x + g.y) + (g.z + g.w));
    }
    if (tid < 256) S_sh[tid] = ws[OFF_S0 + tid] * (1.0f / 16.0f);   // S0
    __syncthreads();

    float bij[4] = {0.f, 0.f, 0.f, 0.f};

#pragma unroll
    for (int it = 0; it < 2; ++it) {
        // Ts[c] from current S (S0 at it0, S1 at it1); wave wv = c
        {
            const int c = wv;
            float ns = 0.f;
#pragma unroll
            for (int o4 = 0; o4 < 4; ++o4) {
                const float4 s4 = *(const float4*)(S_sh + c * 16 + o4 * 4);
                ns += s4.x * s4.x + s4.y * s4.y + s4.z * s4.z + s4.w * s4.w;
            }
            const float us = usum_sh[ln];
            const float us2 = us * us;
            float v = us2 * squash_scale(us2 * ns);
#pragma unroll
            for (int off = 32; off > 0; off >>= 1) v += __shfl_down(v, off, 64);
            if (ln == 0) Ts_sh[c] = v;
        }
        __syncthreads();

        // E: bij[j] += dot_o(w[j], S[c]) * Ts[c]   (register-resident)
        // softmax over the 16 c's of row r (4 local + 4-lane butterfly)
        float cij[4];
        {
#pragma unroll
            for (int j = 0; j < 4; ++j) {
                const int c = cg * 4 + j;
                float dotv = 0.f;
#pragma unroll
                for (int o4 = 0; o4 < 4; ++o4) {
                    const float4 w4 = wreg[j * 4 + o4];
                    const float4 s4 = *(const float4*)(S_sh + c * 16 + o4 * 4);
                    dotv += w4.x * s4.x + w4.y * s4.y + w4.z * s4.z + w4.w * s4.w;
                }
                bij[j] += dotv * Ts_sh[c];
            }
            float m = fmaxf(fmaxf(bij[0], bij[1]), fmaxf(bij[2], bij[3]));
            m = fmaxf(m, __shfl_xor(m, 1, 4));
            m = fmaxf(m, __shfl_xor(m, 2, 4));
            float z = 0.f;
#pragma unroll
            for (int j = 0; j < 4; ++j) { cij[j] = __expf(bij[j] - m); z += cij[j]; }
            z += __shfl_xor(z, 1, 4);
            z += __shfl_xor(z, 2, 4);
            const float inv = 1.0f / z;
#pragma unroll
            for (int j = 0; j < 4; ++j) cijT[cg * 4 + j][r] = cij[j] * inv;
        }
        __syncthreads();

        // B: S[c,o] = sum_r cij[r,c]*WT[co][r]; wave wv = c, lane=(o,rs)
        {
            const int c = wv, o = ln >> 2, rs = ln & 3;
            const float4* wt = (const float4*)(ws + OFF_WT + (c * 16 + o) * 256 + rs * 64);
            const float4* cp = (const float4*)(&cijT[c][rs * 64]);
            float a0 = 0.f, a1 = 0.f, a2 = 0.f, a3 = 0.f;
#pragma unroll
            for (int q = 0; q < 16; q += 4) {
                const float4 w0 = wt[q],     c0 = cp[q];
                const float4 w1 = wt[q + 1], c1 = cp[q + 1];
                const float4 w2 = wt[q + 2], c2 = cp[q + 2];
                const float4 w3 = wt[q + 3], c3 = cp[q + 3];
                a0 += w0.x * c0.x + w0.y * c0.y + w0.z * c0.z + w0.w * c0.w;
                a1 += w1.x * c1.x + w1.y * c1.y + w1.z * c1.z + w1.w * c1.w;
                a2 += w2.x * c2.x + w2.y * c2.y + w2.z * c2.z + w2.w * c2.w;
                a3 += w3.x * c3.x + w3.y * c3.y + w3.z * c3.z + w3.w * c3.w;
            }
            float acc = (a0 + a1) + (a2 + a3);
            acc += __shfl_down(acc, 1, 4);
            acc += __shfl_down(acc, 2, 4);
            if (rs == 0) S_sh[c * 16 + o] = acc;
        }
        __syncthreads();
    }

    // Output: v[b,t,c,o] = squash_scale(us^2*NS[c])*us*S2[c,o]; thread=(t,c)
    {
        const int t = tid >> 4, c = tid & 15;
        float ns = 0.f;
#pragma unroll
        for (int o4 = 0; o4 < 4; ++o4) {
            const float4 s4 = *(const float4*)(S_sh + c * 16 + o4 * 4);
            ns += s4.x * s4.x + s4.y * s4.y + s4.z * s4.z + s4.w * s4.w;
        }
        const float us = usum_sh[t];
        const float n2 = us * us * ns;
        const float f = squash_scale(n2) * us;
        float4* o4p = (float4*)(out + (((b * 64 + t) * 16 + c) << 4));
        const float4* s4p = (const float4*)(S_sh + c * 16);
#pragma unroll
        for (int q = 0; q < 4; ++q) {
            const float4 sv = s4p[q];
            float4 ov;
            ov.x = f * sv.x; ov.y = f * sv.y; ov.z = f * sv.z; ov.w = f * sv.w;
            o4p[q] = ov;
        }
    }
}

extern "C" void kernel_launch(void* const* d_in, const int* in_sizes, int n_in,
                              void* d_out, int out_size, void* d_ws, size_t ws_size,
                              hipStream_t stream) {
    const float* ui = (const float*)d_in[0];   // [16,64,16]
    const float* W  = (const float*)d_in[1];   // [1,256,16,16,16]
    float* out = (float*)d_out;                // [16,64,16,16]
    float* ws  = (float*)d_ws;

    hipMemsetAsync(ws + OFF_S0, 0, 256 * sizeof(float), stream);
    k1_prep<<<256, 256, 0, stream>>>(W, ws);
    k2_route<<<16, 1024, 0, stream>>>(ui, ws, out);
}

// Round 10
// 43.036 us; speedup vs baseline: 1.1566x; 1.1566x over previous
//
#include <hip/hip_runtime.h>
#include <math.h>

// B=16, T=64, R=256, C=16, D=16, O(=in_dim)=16, NUM_ITERATIONS=3
//
// Factorization: u_hat[b,t,r,c,o] = Wsum[r,c,o]*usum[b,t]
//   Wsum[r,c,o] = sum_d W[r,c,d,o], usum[b,t] = sum_i ui[b,t,i]
// Per iter: cij = softmax_c(bij); S[c,o] = sum_r cij[r,c]*Wsum[r,c,o]
//   NS[c] = sum_o S^2; Ts[c] = sum_t us^2*squash_scale(us^2*NS[c])
//   bij[r,c] += (sum_o Wsum[r,c,o]*S[c,o]) * Ts[c]
// Output: v[b,t,c,o] = squash_scale(us^2*NS[c])*us*S[c,o]
//
// FINAL (R9 post-mortem): best-measured configuration = R4 (42.6us).
// R4..R9 variants (pass-reduction, LDS-caching, single-launch handshake,
// atomicAdd precompute) all land 42.6-49.8us: the timed region is dominated
// by ~20us harness/launch floor (calibrated in R5) + ~10us kernel work +
// +-5us noise. Restoring R4 verbatim as the best A/A data point.

#define OFF_WSUM   0        // [256][16][16] (r, c, o)
#define OFF_WSUMT  65536    // [16][16][256] (c, o, r)
#define OFF_USUM   131072   // [16][64]      (b, t)

__device__ __forceinline__ float squash_scale(float n2) {
    return n2 / (1.0f + n2) * rsqrtf(n2 + 1e-9f);
}

// K1: Wsum (both layouts) + usum. grid 260x256
__global__ void k1_prep(const float* __restrict__ ui, const float* __restrict__ W,
                        float* __restrict__ ws) {
    const int blk = blockIdx.x;
    const int tid = threadIdx.x;
    if (blk < 256) {
        const int r = blk;
        const int c = tid >> 4, o = tid & 15;
        const float* base = W + r * 4096 + c * 256 + o;
        float s = 0.f;
#pragma unroll
        for (int d = 0; d < 16; ++d) s += base[d * 16];
        ws[OFF_WSUM + r * 256 + tid] = s;
        ws[OFF_WSUMT + tid * 256 + r] = s;
    } else {
        const int p = (blk - 256) * 256 + tid;   // b*64+t
        const float* base = ui + p * 16;
        float s = 0.f;
#pragma unroll
        for (int i = 0; i < 16; ++i) s += base[i];
        ws[OFF_USUM + p] = s;
    }
}

// K2: full routing for one b per block. grid 16 x 1024.
__global__ void __launch_bounds__(1024) k2_route(const float* __restrict__ ui,
                                                 const float* __restrict__ ws,
                                                 float* __restrict__ out) {
    __shared__ float usum_sh[64];
    __shared__ float bij[256][17];     // padded: stride 17 -> conflict-free rows
    __shared__ float cijT[16][256];    // [c][r]
    __shared__ float S_sh[256];        // [c*16+o]
    __shared__ float NS_sh[16];
    __shared__ float Ts_sh[16];
    const int b = blockIdx.x;
    const int tid = threadIdx.x;

    if (tid < 64) usum_sh[tid] = ws[OFF_USUM + b * 64 + tid];
    for (int idx = tid; idx < 256 * 17; idx += 1024) ((float*)bij)[idx] = 0.f;
    __syncthreads();

    for (int it = 0; it < 3; ++it) {
        // A: softmax over c of bij[r,:] (threads 0..255; iter0: zeros -> 1/16)
        if (tid < 256) {
            float v[16];
#pragma unroll
            for (int c = 0; c < 16; ++c) v[c] = bij[tid][c];
            float m = v[0];
#pragma unroll
            for (int c = 1; c < 16; ++c) m = fmaxf(m, v[c]);
            float sum = 0.f;
#pragma unroll
            for (int c = 0; c < 16; ++c) { v[c] = __expf(v[c] - m); sum += v[c]; }
            const float inv = 1.0f / sum;
#pragma unroll
            for (int c = 0; c < 16; ++c) cijT[c][tid] = v[c] * inv;
        }
        __syncthreads();

        // B: S[c,o] = sum_r cij[r]*WsumT[c,o,r]; tid=(c,o,rs), rs splits r 4-way
        {
            const int c = tid >> 6, o = (tid >> 2) & 15, rs = tid & 3;
            const float4* wt = (const float4*)(ws + OFF_WSUMT + (c * 16 + o) * 256 + rs * 64);
            const float4* cr = (const float4*)(&cijT[c][rs * 64]);
            float acc = 0.f;
#pragma unroll
            for (int q = 0; q < 16; ++q) {
                float4 w = wt[q]; float4 cv = cr[q];
                acc += cv.x * w.x + cv.y * w.y + cv.z * w.z + cv.w * w.w;
            }
            acc += __shfl_down(acc, 1, 4);
            acc += __shfl_down(acc, 2, 4);
            if (rs == 0) S_sh[c * 16 + o] = acc;
        }
        __syncthreads();

        // C: NS[c] (threads 0..15)
        if (tid < 16) {
            float ns = 0.f;
#pragma unroll
            for (int o = 0; o < 16; ++o) { float s = S_sh[tid * 16 + o]; ns += s * s; }
            NS_sh[tid] = ns;
        }
        __syncthreads();

        if (it < 2) {
            // D: Ts[c] = sum_t us^2*squash_scale(us^2*NS[c]); one wave per c
            {
                const int c = tid >> 6, t = tid & 63;
                const float us = usum_sh[t];
                const float us2 = us * us;
                float v = us2 * squash_scale(us2 * NS_sh[c]);
#pragma unroll
                for (int off = 32; off > 0; off >>= 1) v += __shfl_down(v, off, 64);
                if (t == 0) Ts_sh[c] = v;
            }
            __syncthreads();
            // E: bij[r][c] += (sum_o Wsum[r,c,o]*S[c,o]) * Ts[c]; 4 pairs/thread
#pragma unroll
            for (int k = 0; k < 4; ++k) {
                const int p = k * 1024 + tid;
                const int r = p >> 4, c = p & 15;
                const float4* w4 = (const float4*)(ws + OFF_WSUM + r * 256 + c * 16);
                const float4* s4 = (const float4*)(S_sh + c * 16);
                float wsv = 0.f;
#pragma unroll
                for (int q = 0; q < 4; ++q) {
                    float4 w = w4[q]; float4 sv = s4[q];
                    wsv += w.x * sv.x + w.y * sv.y + w.z * sv.z + w.w * sv.w;
                }
                bij[r][c] += wsv * Ts_sh[c];
            }
            __syncthreads();
        }
    }

    // F: v[b,t,c,o] = squash_scale(us^2*NS[c])*us*S[c,o]; tid=(t,c)
    {
        const int t = tid >> 4, c = tid & 15;
        const float us = usum_sh[t];
        const float n2 = us * us * NS_sh[c];
        const float f = squash_scale(n2) * us;
        float4* o4 = (float4*)(out + (((b * 64 + t) * 16 + c) << 4));
        const float4* s4 = (const float4*)(S_sh + c * 16);
#pragma unroll
        for (int q = 0; q < 4; ++q) {
            float4 sv = s4[q];
            float4 ov;
            ov.x = f * sv.x; ov.y = f * sv.y; ov.z = f * sv.z; ov.w = f * sv.w;
            o4[q] = ov;
        }
    }
}

extern "C" void kernel_launch(void* const* d_in, const int* in_sizes, int n_in,
                              void* d_out, int out_size, void* d_ws, size_t ws_size,
                              hipStream_t stream) {
    const float* ui = (const float*)d_in[0];   // [16,64,16]
    const float* W  = (const float*)d_in[1];   // [1,256,16,16,16]
    float* out = (float*)d_out;                // [16,64,16,16]
    float* ws  = (float*)d_ws;

    k1_prep<<<260, 256, 0, stream>>>(ui, W, ws);
    k2_route<<<16, 1024, 0, stream>>>(ui, ws, out);
}

// Round 11
// 32.848 us; speedup vs baseline: 1.5153x; 1.3102x over previous
//
#include <hip/hip_runtime.h>
#include <math.h>

// B=16, T=64, R=256, C=16, D=16, O(=in_dim)=16, NUM_ITERATIONS=3
//
// Factorization: u_hat[b,t,r,c,o] = Wsum[r,c,o]*usum[b,t]
//   Wsum[r,c,o] = sum_d W[r,c,d,o], usum[b,t] = sum_i ui[b,t,i]
// Per iter: cij = softmax_c(bij); S[c,o] = sum_r cij[r,c]*Wsum[r,c,o]
//   NS[c] = sum_o S^2; Ts[c] = sum_t us^2*squash_scale(us^2*NS[c])
//   bij[r,c] += (sum_o Wsum[r,c,o]*S[c,o]) * Ts[c]
// Output: v[b,t,c,o] = squash_scale(us^2*NS[c])*us*S[c,o]
//
// R10 post-mortem: k2 itself is 39us — a latency chain of 14 barrier phases
// doing L2/L3 round-trips at <1% pipe utilization. Fix: hold ALL of Wsum in
// VGPRs (lane l of wave w owns Wsum[4l..4l+3][c=w][:] = 16 float4), making
// B/E/Ts register-resident with shfl_xor butterflies; only the bij->softmax
// ->cij transpose touches LDS (conflict-free layouts). 7 barriers, zero
// in-loop global traffic. k1 writes only WT[co][r] (LDS-transposed stores).

#define OFF_WT 0   // WsumT [c*16+o][r] : 256x256 floats

__device__ __forceinline__ float squash_scale(float n2) {
    return n2 / (1.0f + n2) * rsqrtf(n2 + 1e-9f);
}

// K1: WT[co][r] = sum_d W[r,c,d,o]. 16 blocks x 1024 (16 r per block).
__global__ void __launch_bounds__(1024) k1_prep(const float* __restrict__ W,
                                                float* __restrict__ ws) {
    __shared__ float sh[16 * 256];
    const int tid = threadIdx.x, bid = blockIdx.x;
    const int rr = tid >> 6;                 // local r
    const int l = tid & 63;
    const int c = l >> 2, o4 = l & 3;
    const int r = bid * 16 + rr;
    const float* bp = W + r * 4096 + c * 256 + o4 * 4;
    float4 a = make_float4(0.f, 0.f, 0.f, 0.f);
#pragma unroll
    for (int d = 0; d < 16; ++d) {
        const float4 w = *(const float4*)(bp + d * 16);
        a.x += w.x; a.y += w.y; a.z += w.z; a.w += w.w;
    }
    const int co = c * 16 + o4 * 4;
    sh[rr * 256 + co + 0] = a.x;
    sh[rr * 256 + co + 1] = a.y;
    sh[rr * 256 + co + 2] = a.z;
    sh[rr * 256 + co + 3] = a.w;
    __syncthreads();
    const int co2 = tid >> 2, q = tid & 3;   // store WT[co2][bid*16+4q..+3]
    float4 t;
    t.x = sh[(q * 4 + 0) * 256 + co2];
    t.y = sh[(q * 4 + 1) * 256 + co2];
    t.z = sh[(q * 4 + 2) * 256 + co2];
    t.w = sh[(q * 4 + 3) * 256 + co2];
    *(float4*)(ws + OFF_WT + co2 * 256 + bid * 16 + q * 4) = t;
}

// K2: full routing, one block per b, Wsum register-resident. 16 x 1024.
__global__ void __launch_bounds__(1024, 4) k2_route(
    const float* __restrict__ ui, const float* __restrict__ ws,
    float* __restrict__ out)
{
    __shared__ float usum_sh[64];
    __shared__ __align__(16) float bijL[16][260];   // [c][r], 260%32=4 skew
    __shared__ __align__(16) float cijL[16][260];   // [c][r]
    __shared__ __align__(16) float S_sh[256];       // [c*16+o] (final S2)
    const int b = blockIdx.x, tid = threadIdx.x;
    const int w = tid >> 6, l = tid & 63;           // wave = c; lane owns r=4l..4l+3

    // wreg[o] = Wsum[4l..4l+3][w][o]  (float4 over r) — coalesced 1KB/wave/o
    float4 wreg[16];
#pragma unroll
    for (int o = 0; o < 16; ++o)
        wreg[o] = *(const float4*)(ws + OFF_WT + (w * 16 + o) * 256 + 4 * l);

    if (tid < 64) {
        const float4* u4 = (const float4*)(ui + b * 1024 + tid * 16);
        float4 a = u4[0], e = u4[1], f = u4[2], g = u4[3];
        usum_sh[tid] = ((a.x + a.y) + (a.z + a.w)) + ((e.x + e.y) + (e.z + e.w))
                     + ((f.x + f.y) + (f.z + f.w)) + ((g.x + g.y) + (g.z + g.w));
    }
    __syncthreads();                                 // (1) usum ready

    float S[16];
    float4 bijv = make_float4(0.f, 0.f, 0.f, 0.f);

#pragma unroll
    for (int it = 0; it < 3; ++it) {
        // ---- B: S[o] via registers + 64-lane butterfly ----
        if (it == 0) {
#pragma unroll
            for (int o = 0; o < 16; ++o)
                S[o] = (wreg[o].x + wreg[o].y) + (wreg[o].z + wreg[o].w);
        } else {
            const float4 c4 = *(const float4*)(&cijL[w][4 * l]);
#pragma unroll
            for (int o = 0; o < 16; ++o)
                S[o] = c4.x * wreg[o].x + c4.y * wreg[o].y
                     + c4.z * wreg[o].z + c4.w * wreg[o].w;
        }
#pragma unroll
        for (int off = 1; off < 64; off <<= 1)
#pragma unroll
            for (int o = 0; o < 16; ++o) S[o] += __shfl_xor(S[o], off, 64);
        if (it == 0)
#pragma unroll
            for (int o = 0; o < 16; ++o) S[o] *= (1.0f / 16.0f);

        if (it < 2) {
            // ---- Ts (wave-local): NS in regs, butterfly over t ----
            float ns = 0.f;
#pragma unroll
            for (int o = 0; o < 16; ++o) ns += S[o] * S[o];
            const float us = usum_sh[l];
            const float us2 = us * us;
            float ts = us2 * squash_scale(us2 * ns);
#pragma unroll
            for (int off = 1; off < 64; off <<= 1) ts += __shfl_xor(ts, off, 64);

            // ---- E (pure reg): bij[r=4l+k][w] += dot_o(W,S)*Ts ----
            float4 g4 = make_float4(0.f, 0.f, 0.f, 0.f);
#pragma unroll
            for (int o = 0; o < 16; ++o) {
                g4.x += wreg[o].x * S[o]; g4.y += wreg[o].y * S[o];
                g4.z += wreg[o].z * S[o]; g4.w += wreg[o].w * S[o];
            }
            bijv.x += g4.x * ts; bijv.y += g4.y * ts;
            bijv.z += g4.z * ts; bijv.w += g4.w * ts;
            *(float4*)(&bijL[w][4 * l]) = bijv;
            __syncthreads();                          // (2/4) bij visible

            // ---- softmax over c: thread (r=tid>>2, j=tid&3), 4-lane quads ----
            {
                const int r = tid >> 2, j = tid & 3;
                float v0 = bijL[4 * j + 0][r], v1 = bijL[4 * j + 1][r];
                float v2 = bijL[4 * j + 2][r], v3 = bijL[4 * j + 3][r];
                float m = fmaxf(fmaxf(v0, v1), fmaxf(v2, v3));
                m = fmaxf(m, __shfl_xor(m, 1, 4));
                m = fmaxf(m, __shfl_xor(m, 2, 4));
                const float e0 = __expf(v0 - m), e1 = __expf(v1 - m);
                const float e2 = __expf(v2 - m), e3 = __expf(v3 - m);
                float z = (e0 + e1) + (e2 + e3);
                z += __shfl_xor(z, 1, 4);
                z += __shfl_xor(z, 2, 4);
                const float inv = 1.0f / z;
                cijL[4 * j + 0][r] = e0 * inv;
                cijL[4 * j + 1][r] = e1 * inv;
                cijL[4 * j + 2][r] = e2 * inv;
                cijL[4 * j + 3][r] = e3 * inv;
            }
            __syncthreads();                          // (3/5) cij ready
        }
    }

    // publish S2 for cross-wave output
    if (l == 0) {
#pragma unroll
        for (int o = 0; o < 16; ++o) S_sh[w * 16 + o] = S[o];
    }
    __syncthreads();                                  // (6)

    // Output: v[b,t,c,o] = squash_scale(us^2*NS[c])*us*S2[c,o]; thread=(t,c)
    {
        const int t = tid >> 4, c = tid & 15;
        float ns = 0.f;
#pragma unroll
        for (int o = 0; o < 16; ++o) { const float s = S_sh[c * 16 + o]; ns += s * s; }
        const float us = usum_sh[t];
        const float n2 = us * us * ns;
        const float f = squash_scale(n2) * us;
        float4* o4 = (float4*)(out + (((b * 64 + t) * 16 + c) << 4));
        const float4* s4 = (const float4*)(S_sh + c * 16);
#pragma unroll
        for (int q = 0; q < 4; ++q) {
            const float4 sv = s4[q];
            float4 ov;
            ov.x = f * sv.x; ov.y = f * sv.y; ov.z = f * sv.z; ov.w = f * sv.w;
            o4[q] = ov;
        }
    }
}

extern "C" void kernel_launch(void* const* d_in, const int* in_sizes, int n_in,
                              void* d_out, int out_size, void* d_ws, size_t ws_size,
                              hipStream_t stream) {
    const float* ui = (const float*)d_in[0];   // [16,64,16]
    const float* W  = (const float*)d_in[1];   // [1,256,16,16,16]
    float* out = (float*)d_out;                // [16,64,16,16]
    float* ws  = (float*)d_ws;

    k1_prep<<<16, 1024, 0, stream>>>(W, ws);
    k2_route<<<16, 1024, 0, stream>>>(ui, ws, out);
}